// Round 21
// baseline (156.701 us; speedup 1.0000x reference)
//
#include <hip/hip_runtime.h>

#define C_CH 32
#define CAP 128        // capacity-path csr slots per node
#define CAPB 88        // binned-path csr slots per node (Poisson(32), P(>88)~1e-15)
#define BW_LOG 9
#define BW_N (1 << BW_LOG)   // 512 nodes per dst-bucket
#define EPB 8192             // edges per binning workgroup
#define BIN_T 1024           // binning WG size
#define EPT (EPB / BIN_T)    // 8 edges per thread, cached in registers
#define SRC_BITS 17
#define SRC_MASK 0x1FFFF

// =================== binned-CSR path ===================

// Pack null_mask (int32) into a 12.5KB bitmap -> L1-resident for lp_bin's gathers.
__global__ void lp_packmask(const int* __restrict__ mask,
                            unsigned* __restrict__ bits, int n, int nwords)
{
    int i = blockIdx.x * blockDim.x + threadIdx.x;
    int lane = threadIdx.x & 63;
    bool pred = (i < n) && (mask[i] != 0);
    unsigned long long b = __ballot(pred);
    if (lane == 0) {
        int w0 = i >> 5;
        if (w0 < nwords) bits[w0] = (unsigned)b;
        if (w0 + 1 < nwords) bits[w0 + 1] = (unsigned)(b >> 32);
    }
}

// Two-sweep binning; sweep-1 results (keep flag + dst) cached in registers so
// sweep 2 re-reads nothing. Mask lookups hit the L1-resident bitmap.
__global__ void lp_bin(const unsigned* __restrict__ mask_bits,
                       const int* __restrict__ src_sc, const int* __restrict__ dst_sc,
                       const int* __restrict__ src_fc, const int* __restrict__ dst_fc,
                       int* __restrict__ cursors,   // [2*NB]
                       int* __restrict__ bins,      // [2*NB*BCAP]
                       int E, int NB, int BCAP)
{
    const int g = blockIdx.y;
    const int* __restrict__ src = g ? src_fc : src_sc;
    const int* __restrict__ dst = g ? dst_fc : dst_sc;
    extern __shared__ int lds[];        // lhist[NB] | lbase[NB]
    int* lhist = lds;
    int* lbase = lds + NB;
    const int tid = threadIdx.x;
    const long long e0 = (long long)blockIdx.x * EPB;

    for (int b = tid; b < NB; b += BIN_T) lhist[b] = 0;
    __syncthreads();

    unsigned cached[EPT];               // bit31 = keep, low bits = dst
    #pragma unroll
    for (int k = 0; k < EPT; ++k) {
        long long e = e0 + tid + (long long)k * BIN_T;
        unsigned c = 0;
        if (e < E) {
            int d = dst[e];
            if ((mask_bits[d >> 5] >> (d & 31)) & 1u) {
                c = (unsigned)d | 0x80000000u;
                atomicAdd(&lhist[d >> BW_LOG], 1);
            }
        }
        cached[k] = c;
    }
    __syncthreads();
    for (int b = tid; b < NB; b += BIN_T) {
        int k = lhist[b];
        lbase[b] = k ? atomicAdd(&cursors[g * NB + b], k) : 0;
        lhist[b] = 0;
    }
    __syncthreads();
    #pragma unroll
    for (int k = 0; k < EPT; ++k) {
        unsigned c = cached[k];
        if (c & 0x80000000u) {
            int d = (int)(c & 0x7FFFFFFFu);
            int b = d >> BW_LOG;
            long long e = e0 + tid + (long long)k * BIN_T;
            int slot = atomicAdd(&lhist[b], 1);
            long long pos = (long long)lbase[b] + slot;
            if (pos < BCAP) {
                int packed = (src[e] & SRC_MASK) | ((d & (BW_N - 1)) << SRC_BITS);
                bins[(long long)(g * NB + b) * BCAP + pos] = packed;
            }
        }
    }
}

// One WG per (bucket, graph). Per-node ranks via LDS atomics (no global atomics);
// final counts written once with plain contiguous stores.
__global__ void lp_fill_binned(const int* __restrict__ cursors,
                               const int* __restrict__ bins,
                               int* __restrict__ cnt_sc, int* __restrict__ cnt_fc,
                               int* __restrict__ csr_sc, int* __restrict__ csr_fc,
                               int NB, int BCAP, int n)
{
    const int g = blockIdx.y;
    int* __restrict__ cnt = g ? cnt_fc : cnt_sc;
    int* __restrict__ csr = g ? csr_fc : csr_sc;
    const int b = blockIdx.x;
    __shared__ int lcnt[BW_N];
    for (int i = threadIdx.x; i < BW_N; i += blockDim.x) lcnt[i] = 0;
    __syncthreads();

    int m = min(cursors[g * NB + b], BCAP);
    const int* __restrict__ bb = bins + (long long)(g * NB + b) * BCAP;
    for (int i = threadIdx.x; i < m; i += blockDim.x) {
        int p = bb[i];
        int s = p & SRC_MASK;
        int dl = p >> SRC_BITS;                     // node idx within bucket
        int r = atomicAdd(&lcnt[dl], 1);            // LDS atomic
        if (r < CAPB)
            csr[(long long)((b << BW_LOG) + dl) * CAPB + r] = s;
    }
    __syncthreads();
    int base = b << BW_LOG;
    for (int i = threadIdx.x; i < BW_N; i += blockDim.x) {
        int node = base + i;
        if (node < n) cnt[node] = lcnt[i];
    }
}

// f32 -> bf16 (RNE) side table for the gather-heavy pull.
__global__ void lp_tobf16(const float* __restrict__ in,
                          unsigned short* __restrict__ out, int total)
{
    int i = blockIdx.x * blockDim.x + threadIdx.x;
    if (i < total) {
        unsigned u = __float_as_uint(in[i]);
        unsigned r = (u + 0x7FFF + ((u >> 16) & 1)) >> 16;
        out[i] = (unsigned short)r;
    }
}

// 8 lanes per node; both graphs' gather streams interleaved for 2x MLP.
__global__ void lp_pull8(const float* __restrict__ lbls,
                         const unsigned short* __restrict__ lb16,
                         const int* __restrict__ null_mask,
                         const int* __restrict__ cnt_sc, const int* __restrict__ csr_sc,
                         const int* __restrict__ cnt_fc, const int* __restrict__ csr_fc,
                         float* __restrict__ out, int n, int cap)
{
    int t = blockIdx.x * blockDim.x + threadIdx.x;
    int node = t >> 3;
    int lane = t & 7;
    if (node >= n) return;

    long long obase = (long long)node * C_CH + lane * 4;
    if (!null_mask[node]) {
        float4 v = *reinterpret_cast<const float4*>(lbls + obase);
        *reinterpret_cast<float4*>(out + obase) = v;
        return;
    }

    int m0 = min(cnt_sc[node], cap);
    int m1 = min(cnt_fc[node], cap);
    const int* row0 = csr_sc + (long long)node * cap;
    const int* row1 = csr_fc + (long long)node * cap;

    float a0 = 0.f, a1 = 0.f, a2 = 0.f, a3 = 0.f;   // graph 0 accum
    float b0 = 0.f, b1 = 0.f, b2 = 0.f, b3 = 0.f;   // graph 1 accum
    int mmax = max(m0, m1);
    for (int base = 0; base < mmax; base += 8) {
        int sidx0 = (base + lane < m0) ? row0[base + lane] : 0;
        int sidx1 = (base + lane < m1) ? row1[base + lane] : 0;
        int lim0 = m0 - base;                        // may exceed 8 or be <=0
        int lim1 = m1 - base;
        #pragma unroll
        for (int k = 0; k < 8; ++k) {
            int s0 = __shfl(sidx0, k, 8);
            int s1 = __shfl(sidx1, k, 8);
            if (k < lim0) {
                ushort4 v = *reinterpret_cast<const ushort4*>(
                    lb16 + (long long)s0 * C_CH + lane * 4);
                a0 += __uint_as_float((unsigned)v.x << 16);
                a1 += __uint_as_float((unsigned)v.y << 16);
                a2 += __uint_as_float((unsigned)v.z << 16);
                a3 += __uint_as_float((unsigned)v.w << 16);
            }
            if (k < lim1) {
                ushort4 v = *reinterpret_cast<const ushort4*>(
                    lb16 + (long long)s1 * C_CH + lane * 4);
                b0 += __uint_as_float((unsigned)v.x << 16);
                b1 += __uint_as_float((unsigned)v.y << 16);
                b2 += __uint_as_float((unsigned)v.z << 16);
                b3 += __uint_as_float((unsigned)v.w << 16);
            }
        }
    }
    float inv0 = 1.0f / fmaxf((float)m0, 1.0f);
    float inv1 = 1.0f / fmaxf((float)m1, 1.0f);
    float4 o;
    o.x = (a0 * inv0 + b0 * inv1) * 0.5f;
    o.y = (a1 * inv0 + b1 * inv1) * 0.5f;
    o.z = (a2 * inv0 + b2 * inv1) * 0.5f;
    o.w = (a3 * inv0 + b3 * inv1) * 0.5f;
    *reinterpret_cast<float4*>(out + obase) = o;
}

// =================== capacity-CSR path (fallback #1) ===================

__global__ void lp_fill_cap(const int* __restrict__ null_mask,
                            const int* __restrict__ src_sc, const int* __restrict__ dst_sc,
                            const int* __restrict__ src_fc, const int* __restrict__ dst_fc,
                            int* __restrict__ cnt_sc, int* __restrict__ cnt_fc,
                            int* __restrict__ csr_sc, int* __restrict__ csr_fc, int E)
{
    const int g = blockIdx.y;
    const int* __restrict__ src = g ? src_fc : src_sc;
    const int* __restrict__ dst = g ? dst_fc : dst_sc;
    int* __restrict__ cnt = g ? cnt_fc : cnt_sc;
    int* __restrict__ csr = g ? csr_fc : csr_sc;
    int e = blockIdx.x * blockDim.x + threadIdx.x;
    if (e >= E) return;
    int d = dst[e];
    if (!null_mask[d]) return;
    int r = atomicAdd(&cnt[d], 1);
    if (r < CAP) csr[(long long)d * CAP + r] = src[e];
}

__global__ void lp_pull_cap(const float* __restrict__ lbls,
                            const int* __restrict__ null_mask,
                            const int* __restrict__ cnt_sc, const int* __restrict__ csr_sc,
                            const int* __restrict__ cnt_fc, const int* __restrict__ csr_fc,
                            float* __restrict__ out, int n, int cap)
{
    int node = (blockIdx.x * blockDim.x + threadIdx.x) >> 5;
    int lane = threadIdx.x & 31;
    if (node >= n) return;
    long long obase = (long long)node * C_CH + lane;
    if (!null_mask[node]) {
        out[obase] = lbls[obase];
        return;
    }
    float means[2];
    #pragma unroll
    for (int g = 0; g < 2; ++g) {
        const int* __restrict__ cnt = g ? cnt_fc : cnt_sc;
        const int* __restrict__ csr = g ? csr_fc : csr_sc;
        int m = min(cnt[node], cap);
        const int* row = csr + (long long)node * cap;
        float acc = 0.0f;
        for (int base = 0; base < m; base += 32) {
            int sidx = (base + lane < m) ? row[base + lane] : 0;
            int lim = min(32, m - base);
            if (lim == 32) {
                #pragma unroll
                for (int k = 0; k < 32; ++k) {
                    int s = __shfl(sidx, k, 32);
                    acc += lbls[(long long)s * C_CH + lane];
                }
            } else {
                for (int k = 0; k < lim; ++k) {
                    int s = __shfl(sidx, k, 32);
                    acc += lbls[(long long)s * C_CH + lane];
                }
            }
        }
        means[g] = acc / fmaxf((float)m, 1.0f);
    }
    out[obase] = 0.5f * (means[0] + means[1]);
}

// =================== push-atomic path (fallback #2) ===================

__global__ void lp_scatter(const float* __restrict__ lbls,
                           const int* __restrict__ null_mask,
                           const int* __restrict__ src_sc, const int* __restrict__ dst_sc,
                           const int* __restrict__ src_fc, const int* __restrict__ dst_fc,
                           float* __restrict__ sums_sc, float* __restrict__ cnt_sc,
                           float* __restrict__ sums_fc, float* __restrict__ cnt_fc,
                           int E)
{
    const int g = blockIdx.y;
    const int* __restrict__ src = g ? src_fc : src_sc;
    const int* __restrict__ dst = g ? dst_fc : dst_sc;
    float* __restrict__ sums = g ? sums_fc : sums_sc;
    float* __restrict__ cnt  = g ? cnt_fc  : cnt_sc;
    long long tid = (long long)blockIdx.x * blockDim.x + threadIdx.x;
    long long e = tid >> 3;
    int sub = (int)(tid & 7);
    if (e >= E) return;
    int d = dst[e];
    if (!null_mask[d]) return;
    int s = src[e];
    const float4 v = *reinterpret_cast<const float4*>(lbls + (long long)s * C_CH + sub * 4);
    float* base = sums + (long long)d * C_CH + sub * 4;
    atomicAdd(base + 0, v.x);
    atomicAdd(base + 1, v.y);
    atomicAdd(base + 2, v.z);
    atomicAdd(base + 3, v.w);
    if (sub == 0) atomicAdd(cnt + d, 1.0f);
}

__global__ void lp_finalize(const float* __restrict__ lbls,
                            const int* __restrict__ null_mask,
                            const float* __restrict__ sums_sc, const float* __restrict__ cnt_sc,
                            const float* __restrict__ sums_fc, const float* __restrict__ cnt_fc,
                            float* __restrict__ out, int n)
{
    long long tid = (long long)blockIdx.x * blockDim.x + threadIdx.x;
    long long node = tid >> 3;
    int sub = (int)(tid & 7);
    if (node >= n) return;
    long long off = node * C_CH + sub * 4;
    float4 o;
    if (null_mask[node]) {
        float inv1 = 1.0f / fmaxf(cnt_sc[node], 1.0f);
        float inv2 = 1.0f / fmaxf(cnt_fc[node], 1.0f);
        float4 s1 = *reinterpret_cast<const float4*>(sums_sc + off);
        float4 s2 = *reinterpret_cast<const float4*>(sums_fc + off);
        o.x = (s1.x * inv1 + s2.x * inv2) * 0.5f;
        o.y = (s1.y * inv1 + s2.y * inv2) * 0.5f;
        o.z = (s1.z * inv1 + s2.z * inv2) * 0.5f;
        o.w = (s1.w * inv1 + s2.w * inv2) * 0.5f;
    } else {
        o = *reinterpret_cast<const float4*>(lbls + off);
    }
    *reinterpret_cast<float4*>(out + off) = o;
}

// =================== launch ===================

extern "C" void kernel_launch(void* const* d_in, const int* in_sizes, int n_in,
                              void* d_out, int out_size, void* d_ws, size_t ws_size,
                              hipStream_t stream) {
    const float* lbls    = (const float*)d_in[0];
    const int* null_mask = (const int*)d_in[1];   // jax bool -> int32 on the wire
    const int* src_sc    = (const int*)d_in[2];
    const int* dst_sc    = (const int*)d_in[3];
    const int* src_fc    = (const int*)d_in[4];
    const int* dst_fc    = (const int*)d_in[5];
    float* out           = (float*)d_out;

    const int n = in_sizes[1];      // 100000 nodes
    const int E = in_sizes[2];      // 3.2M edges per graph

    // ---- binned path sizing
    const int NB = (n + BW_N - 1) >> BW_LOG;
    const int BCAP = (int)((long long)E * BW_N / n) + 2048;
    const int NWORDS = (n + 31) / 32;
    size_t binned_needed = ((size_t)2 * n + (size_t)2 * NB
                            + (size_t)2 * NB * BCAP + (size_t)2 * n * CAPB) * sizeof(int)
                           + (size_t)n * C_CH * sizeof(unsigned short)
                           + (size_t)NWORDS * sizeof(unsigned);
    size_t lds_bytes = (size_t)2 * NB * sizeof(int);
    bool bin_ok = (n <= (1 << SRC_BITS)) && (lds_bytes <= 60 * 1024) && NB <= 65535;

    size_t cap_needed = ((size_t)2 * n + (size_t)2 * n * CAP) * sizeof(int);
    bool deg_ok = ((long long)E / n) * 3 + 32 <= CAP;

    if (ws_size >= binned_needed && bin_ok) {
        int* cnt_sc  = (int*)d_ws;
        int* cnt_fc  = cnt_sc + n;
        int* cursors = cnt_fc + n;
        int* bins    = cursors + (size_t)2 * NB;
        int* csr_sc  = bins + (size_t)2 * NB * BCAP;
        int* csr_fc  = csr_sc + (size_t)n * CAPB;
        unsigned short* lb16 = (unsigned short*)(csr_fc + (size_t)n * CAPB);
        unsigned* mask_bits = (unsigned*)(lb16 + (size_t)n * C_CH);

        // only cursors need zeroing (fill writes every cnt slot)
        hipMemsetAsync(cursors, 0, (size_t)2 * NB * sizeof(int), stream);

        int total16 = n * C_CH;
        lp_tobf16<<<(total16 + 255) / 256, 256, 0, stream>>>(lbls, lb16, total16);
        lp_packmask<<<(n + 255) / 256, 256, 0, stream>>>(null_mask, mask_bits, n, NWORDS);

        int nwg_bin = (E + EPB - 1) / EPB;
        lp_bin<<<dim3(nwg_bin, 2), BIN_T, (int)lds_bytes, stream>>>(
            mask_bits, src_sc, dst_sc, src_fc, dst_fc, cursors, bins, E, NB, BCAP);
        lp_fill_binned<<<dim3(NB, 2), 256, 0, stream>>>(
            cursors, bins, cnt_sc, cnt_fc, csr_sc, csr_fc, NB, BCAP, n);

        int nb = 256;
        int nblocks = (int)(((long long)n * 8 + nb - 1) / nb);
        lp_pull8<<<nblocks, nb, 0, stream>>>(lbls, lb16, null_mask,
                                             cnt_sc, csr_sc, cnt_fc, csr_fc,
                                             out, n, CAPB);
    } else if (ws_size >= cap_needed && deg_ok) {
        int* cnt_sc = (int*)d_ws;
        int* cnt_fc = cnt_sc + n;
        int* csr_sc = cnt_fc + n;
        int* csr_fc = csr_sc + (size_t)n * CAP;

        hipMemsetAsync(cnt_sc, 0, (size_t)2 * n * sizeof(int), stream);

        int eb = 256;
        int eblocks = (E + eb - 1) / eb;
        lp_fill_cap<<<dim3(eblocks, 2), eb, 0, stream>>>(null_mask,
                                                         src_sc, dst_sc, src_fc, dst_fc,
                                                         cnt_sc, cnt_fc, csr_sc, csr_fc, E);
        int nb = 256;
        int nblocks = (int)(((long long)n * 32 + nb - 1) / nb);
        lp_pull_cap<<<nblocks, nb, 0, stream>>>(lbls, null_mask,
                                                cnt_sc, csr_sc, cnt_fc, csr_fc,
                                                out, n, CAP);
    } else {
        float* sums_sc = (float*)d_ws;
        float* sums_fc = sums_sc + (size_t)n * C_CH;
        float* cnt_sc  = sums_fc + (size_t)n * C_CH;
        float* cnt_fc  = cnt_sc + n;
        size_t ws_needed_bytes = ((size_t)n * C_CH * 2 + (size_t)n * 2) * sizeof(float);
        hipMemsetAsync(d_ws, 0, ws_needed_bytes, stream);

        long long threads = (long long)E * 8;
        int block = 256;
        int blocks = (int)((threads + block - 1) / block);
        lp_scatter<<<dim3(blocks, 2), block, 0, stream>>>(lbls, null_mask,
                                                          src_sc, dst_sc, src_fc, dst_fc,
                                                          sums_sc, cnt_sc, sums_fc, cnt_fc, E);
        long long fthreads = (long long)n * 8;
        int fblocks = (int)((fthreads + block - 1) / block);
        lp_finalize<<<fblocks, block, 0, stream>>>(lbls, null_mask,
                                                   sums_sc, cnt_sc, sums_fc, cnt_fc,
                                                   out, n);
    }
}

// Round 22
// 156.648 us; speedup vs baseline: 1.0003x; 1.0003x over previous
//
#include <hip/hip_runtime.h>

#define C_CH 32
#define CAP 128        // capacity-path csr slots per node
#define CAPB 88        // binned-path csr slots per node (Poisson(32), P(>88)~1e-15)
#define BW_LOG 9
#define BW_N (1 << BW_LOG)   // 512 nodes per dst-bucket
#define EPB 8192             // edges per binning workgroup
#define BIN_T 1024           // binning WG size
#define EPT (EPB / BIN_T)    // 8 edges per thread, cached in registers
#define SRC_BITS 17
#define SRC_MASK 0x1FFFF

// =================== binned-CSR path ===================

// Pack null_mask (int32) into a 12.5KB bitmap -> L1-resident for lp_bin's gathers.
__global__ void lp_packmask(const int* __restrict__ mask,
                            unsigned* __restrict__ bits, int n, int nwords)
{
    int i = blockIdx.x * blockDim.x + threadIdx.x;
    int lane = threadIdx.x & 63;
    bool pred = (i < n) && (mask[i] != 0);
    unsigned long long b = __ballot(pred);
    if (lane == 0) {
        int w0 = i >> 5;
        if (w0 < nwords) bits[w0] = (unsigned)b;
        if (w0 + 1 < nwords) bits[w0 + 1] = (unsigned)(b >> 32);
    }
}

// Two-sweep binning; sweep-1 results (keep flag + dst) cached in registers so
// sweep 2 re-reads nothing. Mask lookups hit the L1-resident bitmap.
__global__ void lp_bin(const unsigned* __restrict__ mask_bits,
                       const int* __restrict__ src_sc, const int* __restrict__ dst_sc,
                       const int* __restrict__ src_fc, const int* __restrict__ dst_fc,
                       int* __restrict__ cursors,   // [2*NB]
                       int* __restrict__ bins,      // [2*NB*BCAP]
                       int E, int NB, int BCAP)
{
    const int g = blockIdx.y;
    const int* __restrict__ src = g ? src_fc : src_sc;
    const int* __restrict__ dst = g ? dst_fc : dst_sc;
    extern __shared__ int lds[];        // lhist[NB] | lbase[NB]
    int* lhist = lds;
    int* lbase = lds + NB;
    const int tid = threadIdx.x;
    const long long e0 = (long long)blockIdx.x * EPB;

    for (int b = tid; b < NB; b += BIN_T) lhist[b] = 0;
    __syncthreads();

    unsigned cached[EPT];               // bit31 = keep, low bits = dst
    #pragma unroll
    for (int k = 0; k < EPT; ++k) {
        long long e = e0 + tid + (long long)k * BIN_T;
        unsigned c = 0;
        if (e < E) {
            int d = dst[e];
            if ((mask_bits[d >> 5] >> (d & 31)) & 1u) {
                c = (unsigned)d | 0x80000000u;
                atomicAdd(&lhist[d >> BW_LOG], 1);
            }
        }
        cached[k] = c;
    }
    __syncthreads();
    for (int b = tid; b < NB; b += BIN_T) {
        int k = lhist[b];
        lbase[b] = k ? atomicAdd(&cursors[g * NB + b], k) : 0;
        lhist[b] = 0;
    }
    __syncthreads();
    #pragma unroll
    for (int k = 0; k < EPT; ++k) {
        unsigned c = cached[k];
        if (c & 0x80000000u) {
            int d = (int)(c & 0x7FFFFFFFu);
            int b = d >> BW_LOG;
            long long e = e0 + tid + (long long)k * BIN_T;
            int slot = atomicAdd(&lhist[b], 1);
            long long pos = (long long)lbase[b] + slot;
            if (pos < BCAP) {
                int packed = (src[e] & SRC_MASK) | ((d & (BW_N - 1)) << SRC_BITS);
                bins[(long long)(g * NB + b) * BCAP + pos] = packed;
            }
        }
    }
}

// One WG per (bucket, graph). Per-node ranks via LDS atomics (no global atomics);
// final counts written once with plain contiguous stores.
__global__ void lp_fill_binned(const int* __restrict__ cursors,
                               const int* __restrict__ bins,
                               int* __restrict__ cnt_sc, int* __restrict__ cnt_fc,
                               int* __restrict__ csr_sc, int* __restrict__ csr_fc,
                               int NB, int BCAP, int n)
{
    const int g = blockIdx.y;
    int* __restrict__ cnt = g ? cnt_fc : cnt_sc;
    int* __restrict__ csr = g ? csr_fc : csr_sc;
    const int b = blockIdx.x;
    __shared__ int lcnt[BW_N];
    for (int i = threadIdx.x; i < BW_N; i += blockDim.x) lcnt[i] = 0;
    __syncthreads();

    int m = min(cursors[g * NB + b], BCAP);
    const int* __restrict__ bb = bins + (long long)(g * NB + b) * BCAP;
    for (int i = threadIdx.x; i < m; i += blockDim.x) {
        int p = bb[i];
        int s = p & SRC_MASK;
        int dl = p >> SRC_BITS;                     // node idx within bucket
        int r = atomicAdd(&lcnt[dl], 1);            // LDS atomic
        if (r < CAPB)
            csr[(long long)((b << BW_LOG) + dl) * CAPB + r] = s;
    }
    __syncthreads();
    int base = b << BW_LOG;
    for (int i = threadIdx.x; i < BW_N; i += blockDim.x) {
        int node = base + i;
        if (node < n) cnt[node] = lcnt[i];
    }
}

// f32 -> bf16 (RNE) side table for the gather-heavy pull.
__global__ void lp_tobf16(const float* __restrict__ in,
                          unsigned short* __restrict__ out, int total)
{
    int i = blockIdx.x * blockDim.x + threadIdx.x;
    if (i < total) {
        unsigned u = __float_as_uint(in[i]);
        unsigned r = (u + 0x7FFF + ((u >> 16) & 1)) >> 16;
        out[i] = (unsigned short)r;
    }
}

// 8 lanes per node. Joint branch-free chunks over min(m0,m1): 16 unconditional
// gathers in flight; per-graph tails use the proven unconditional 8-load path.
__global__ void lp_pull8(const float* __restrict__ lbls,
                         const unsigned short* __restrict__ lb16,
                         const int* __restrict__ null_mask,
                         const int* __restrict__ cnt_sc, const int* __restrict__ csr_sc,
                         const int* __restrict__ cnt_fc, const int* __restrict__ csr_fc,
                         float* __restrict__ out, int n, int cap)
{
    int t = blockIdx.x * blockDim.x + threadIdx.x;
    int node = t >> 3;
    int lane = t & 7;
    if (node >= n) return;

    long long obase = (long long)node * C_CH + lane * 4;
    if (!null_mask[node]) {
        float4 v = *reinterpret_cast<const float4*>(lbls + obase);
        *reinterpret_cast<float4*>(out + obase) = v;
        return;
    }

    int m0 = min(cnt_sc[node], cap);
    int m1 = min(cnt_fc[node], cap);
    const int* row0 = csr_sc + (long long)node * cap;
    const int* row1 = csr_fc + (long long)node * cap;

    float a0 = 0.f, a1 = 0.f, a2 = 0.f, a3 = 0.f;   // graph 0 accum
    float b0 = 0.f, b1 = 0.f, b2 = 0.f, b3 = 0.f;   // graph 1 accum

    int mmin = min(m0, m1);
    int base = 0;
    // joint full chunks: branch-free, 16 loads in flight
    for (; base + 8 <= mmin; base += 8) {
        int sidx0 = row0[base + lane];
        int sidx1 = row1[base + lane];
        #pragma unroll
        for (int k = 0; k < 8; ++k) {
            int s0 = __shfl(sidx0, k, 8);
            int s1 = __shfl(sidx1, k, 8);
            ushort4 v0 = *reinterpret_cast<const ushort4*>(
                lb16 + (long long)s0 * C_CH + lane * 4);
            ushort4 v1 = *reinterpret_cast<const ushort4*>(
                lb16 + (long long)s1 * C_CH + lane * 4);
            a0 += __uint_as_float((unsigned)v0.x << 16);
            a1 += __uint_as_float((unsigned)v0.y << 16);
            a2 += __uint_as_float((unsigned)v0.z << 16);
            a3 += __uint_as_float((unsigned)v0.w << 16);
            b0 += __uint_as_float((unsigned)v1.x << 16);
            b1 += __uint_as_float((unsigned)v1.y << 16);
            b2 += __uint_as_float((unsigned)v1.z << 16);
            b3 += __uint_as_float((unsigned)v1.w << 16);
        }
    }
    // graph-0 tail
    for (int bb = base; bb < m0; bb += 8) {
        int sidx = (bb + lane < m0) ? row0[bb + lane] : 0;
        int lim = min(8, m0 - bb);
        if (lim == 8) {
            #pragma unroll
            for (int k = 0; k < 8; ++k) {
                int s = __shfl(sidx, k, 8);
                ushort4 v = *reinterpret_cast<const ushort4*>(
                    lb16 + (long long)s * C_CH + lane * 4);
                a0 += __uint_as_float((unsigned)v.x << 16);
                a1 += __uint_as_float((unsigned)v.y << 16);
                a2 += __uint_as_float((unsigned)v.z << 16);
                a3 += __uint_as_float((unsigned)v.w << 16);
            }
        } else {
            for (int k = 0; k < lim; ++k) {
                int s = __shfl(sidx, k, 8);
                ushort4 v = *reinterpret_cast<const ushort4*>(
                    lb16 + (long long)s * C_CH + lane * 4);
                a0 += __uint_as_float((unsigned)v.x << 16);
                a1 += __uint_as_float((unsigned)v.y << 16);
                a2 += __uint_as_float((unsigned)v.z << 16);
                a3 += __uint_as_float((unsigned)v.w << 16);
            }
        }
    }
    // graph-1 tail
    for (int bb = base; bb < m1; bb += 8) {
        int sidx = (bb + lane < m1) ? row1[bb + lane] : 0;
        int lim = min(8, m1 - bb);
        if (lim == 8) {
            #pragma unroll
            for (int k = 0; k < 8; ++k) {
                int s = __shfl(sidx, k, 8);
                ushort4 v = *reinterpret_cast<const ushort4*>(
                    lb16 + (long long)s * C_CH + lane * 4);
                b0 += __uint_as_float((unsigned)v.x << 16);
                b1 += __uint_as_float((unsigned)v.y << 16);
                b2 += __uint_as_float((unsigned)v.z << 16);
                b3 += __uint_as_float((unsigned)v.w << 16);
            }
        } else {
            for (int k = 0; k < lim; ++k) {
                int s = __shfl(sidx, k, 8);
                ushort4 v = *reinterpret_cast<const ushort4*>(
                    lb16 + (long long)s * C_CH + lane * 4);
                b0 += __uint_as_float((unsigned)v.x << 16);
                b1 += __uint_as_float((unsigned)v.y << 16);
                b2 += __uint_as_float((unsigned)v.z << 16);
                b3 += __uint_as_float((unsigned)v.w << 16);
            }
        }
    }

    float inv0 = 1.0f / fmaxf((float)m0, 1.0f);
    float inv1 = 1.0f / fmaxf((float)m1, 1.0f);
    float4 o;
    o.x = (a0 * inv0 + b0 * inv1) * 0.5f;
    o.y = (a1 * inv0 + b1 * inv1) * 0.5f;
    o.z = (a2 * inv0 + b2 * inv1) * 0.5f;
    o.w = (a3 * inv0 + b3 * inv1) * 0.5f;
    *reinterpret_cast<float4*>(out + obase) = o;
}

// =================== capacity-CSR path (fallback #1) ===================

__global__ void lp_fill_cap(const int* __restrict__ null_mask,
                            const int* __restrict__ src_sc, const int* __restrict__ dst_sc,
                            const int* __restrict__ src_fc, const int* __restrict__ dst_fc,
                            int* __restrict__ cnt_sc, int* __restrict__ cnt_fc,
                            int* __restrict__ csr_sc, int* __restrict__ csr_fc, int E)
{
    const int g = blockIdx.y;
    const int* __restrict__ src = g ? src_fc : src_sc;
    const int* __restrict__ dst = g ? dst_fc : dst_sc;
    int* __restrict__ cnt = g ? cnt_fc : cnt_sc;
    int* __restrict__ csr = g ? csr_fc : csr_sc;
    int e = blockIdx.x * blockDim.x + threadIdx.x;
    if (e >= E) return;
    int d = dst[e];
    if (!null_mask[d]) return;
    int r = atomicAdd(&cnt[d], 1);
    if (r < CAP) csr[(long long)d * CAP + r] = src[e];
}

__global__ void lp_pull_cap(const float* __restrict__ lbls,
                            const int* __restrict__ null_mask,
                            const int* __restrict__ cnt_sc, const int* __restrict__ csr_sc,
                            const int* __restrict__ cnt_fc, const int* __restrict__ csr_fc,
                            float* __restrict__ out, int n, int cap)
{
    int node = (blockIdx.x * blockDim.x + threadIdx.x) >> 5;
    int lane = threadIdx.x & 31;
    if (node >= n) return;
    long long obase = (long long)node * C_CH + lane;
    if (!null_mask[node]) {
        out[obase] = lbls[obase];
        return;
    }
    float means[2];
    #pragma unroll
    for (int g = 0; g < 2; ++g) {
        const int* __restrict__ cnt = g ? cnt_fc : cnt_sc;
        const int* __restrict__ csr = g ? csr_fc : csr_sc;
        int m = min(cnt[node], cap);
        const int* row = csr + (long long)node * cap;
        float acc = 0.0f;
        for (int base = 0; base < m; base += 32) {
            int sidx = (base + lane < m) ? row[base + lane] : 0;
            int lim = min(32, m - base);
            if (lim == 32) {
                #pragma unroll
                for (int k = 0; k < 32; ++k) {
                    int s = __shfl(sidx, k, 32);
                    acc += lbls[(long long)s * C_CH + lane];
                }
            } else {
                for (int k = 0; k < lim; ++k) {
                    int s = __shfl(sidx, k, 32);
                    acc += lbls[(long long)s * C_CH + lane];
                }
            }
        }
        means[g] = acc / fmaxf((float)m, 1.0f);
    }
    out[obase] = 0.5f * (means[0] + means[1]);
}

// =================== push-atomic path (fallback #2) ===================

__global__ void lp_scatter(const float* __restrict__ lbls,
                           const int* __restrict__ null_mask,
                           const int* __restrict__ src_sc, const int* __restrict__ dst_sc,
                           const int* __restrict__ src_fc, const int* __restrict__ dst_fc,
                           float* __restrict__ sums_sc, float* __restrict__ cnt_sc,
                           float* __restrict__ sums_fc, float* __restrict__ cnt_fc,
                           int E)
{
    const int g = blockIdx.y;
    const int* __restrict__ src = g ? src_fc : src_sc;
    const int* __restrict__ dst = g ? dst_fc : dst_sc;
    float* __restrict__ sums = g ? sums_fc : sums_sc;
    float* __restrict__ cnt  = g ? cnt_fc  : cnt_sc;
    long long tid = (long long)blockIdx.x * blockDim.x + threadIdx.x;
    long long e = tid >> 3;
    int sub = (int)(tid & 7);
    if (e >= E) return;
    int d = dst[e];
    if (!null_mask[d]) return;
    int s = src[e];
    const float4 v = *reinterpret_cast<const float4*>(lbls + (long long)s * C_CH + sub * 4);
    float* base = sums + (long long)d * C_CH + sub * 4;
    atomicAdd(base + 0, v.x);
    atomicAdd(base + 1, v.y);
    atomicAdd(base + 2, v.z);
    atomicAdd(base + 3, v.w);
    if (sub == 0) atomicAdd(cnt + d, 1.0f);
}

__global__ void lp_finalize(const float* __restrict__ lbls,
                            const int* __restrict__ null_mask,
                            const float* __restrict__ sums_sc, const float* __restrict__ cnt_sc,
                            const float* __restrict__ sums_fc, const float* __restrict__ cnt_fc,
                            float* __restrict__ out, int n)
{
    long long tid = (long long)blockIdx.x * blockDim.x + threadIdx.x;
    long long node = tid >> 3;
    int sub = (int)(tid & 7);
    if (node >= n) return;
    long long off = node * C_CH + sub * 4;
    float4 o;
    if (null_mask[node]) {
        float inv1 = 1.0f / fmaxf(cnt_sc[node], 1.0f);
        float inv2 = 1.0f / fmaxf(cnt_fc[node], 1.0f);
        float4 s1 = *reinterpret_cast<const float4*>(sums_sc + off);
        float4 s2 = *reinterpret_cast<const float4*>(sums_fc + off);
        o.x = (s1.x * inv1 + s2.x * inv2) * 0.5f;
        o.y = (s1.y * inv1 + s2.y * inv2) * 0.5f;
        o.z = (s1.z * inv1 + s2.z * inv2) * 0.5f;
        o.w = (s1.w * inv1 + s2.w * inv2) * 0.5f;
    } else {
        o = *reinterpret_cast<const float4*>(lbls + off);
    }
    *reinterpret_cast<float4*>(out + off) = o;
}

// =================== launch ===================

extern "C" void kernel_launch(void* const* d_in, const int* in_sizes, int n_in,
                              void* d_out, int out_size, void* d_ws, size_t ws_size,
                              hipStream_t stream) {
    const float* lbls    = (const float*)d_in[0];
    const int* null_mask = (const int*)d_in[1];   // jax bool -> int32 on the wire
    const int* src_sc    = (const int*)d_in[2];
    const int* dst_sc    = (const int*)d_in[3];
    const int* src_fc    = (const int*)d_in[4];
    const int* dst_fc    = (const int*)d_in[5];
    float* out           = (float*)d_out;

    const int n = in_sizes[1];      // 100000 nodes
    const int E = in_sizes[2];      // 3.2M edges per graph

    // ---- binned path sizing
    const int NB = (n + BW_N - 1) >> BW_LOG;
    const int BCAP = (int)((long long)E * BW_N / n) + 2048;
    const int NWORDS = (n + 31) / 32;
    size_t binned_needed = ((size_t)2 * n + (size_t)2 * NB
                            + (size_t)2 * NB * BCAP + (size_t)2 * n * CAPB) * sizeof(int)
                           + (size_t)n * C_CH * sizeof(unsigned short)
                           + (size_t)NWORDS * sizeof(unsigned);
    size_t lds_bytes = (size_t)2 * NB * sizeof(int);
    bool bin_ok = (n <= (1 << SRC_BITS)) && (lds_bytes <= 60 * 1024) && NB <= 65535;

    size_t cap_needed = ((size_t)2 * n + (size_t)2 * n * CAP) * sizeof(int);
    bool deg_ok = ((long long)E / n) * 3 + 32 <= CAP;

    if (ws_size >= binned_needed && bin_ok) {
        int* cnt_sc  = (int*)d_ws;
        int* cnt_fc  = cnt_sc + n;
        int* cursors = cnt_fc + n;
        int* bins    = cursors + (size_t)2 * NB;
        int* csr_sc  = bins + (size_t)2 * NB * BCAP;
        int* csr_fc  = csr_sc + (size_t)n * CAPB;
        unsigned short* lb16 = (unsigned short*)(csr_fc + (size_t)n * CAPB);
        unsigned* mask_bits = (unsigned*)(lb16 + (size_t)n * C_CH);

        // only cursors need zeroing (fill writes every cnt slot)
        hipMemsetAsync(cursors, 0, (size_t)2 * NB * sizeof(int), stream);

        int total16 = n * C_CH;
        lp_tobf16<<<(total16 + 255) / 256, 256, 0, stream>>>(lbls, lb16, total16);
        lp_packmask<<<(n + 255) / 256, 256, 0, stream>>>(null_mask, mask_bits, n, NWORDS);

        int nwg_bin = (E + EPB - 1) / EPB;
        lp_bin<<<dim3(nwg_bin, 2), BIN_T, (int)lds_bytes, stream>>>(
            mask_bits, src_sc, dst_sc, src_fc, dst_fc, cursors, bins, E, NB, BCAP);
        lp_fill_binned<<<dim3(NB, 2), 256, 0, stream>>>(
            cursors, bins, cnt_sc, cnt_fc, csr_sc, csr_fc, NB, BCAP, n);

        int nb = 256;
        int nblocks = (int)(((long long)n * 8 + nb - 1) / nb);
        lp_pull8<<<nblocks, nb, 0, stream>>>(lbls, lb16, null_mask,
                                             cnt_sc, csr_sc, cnt_fc, csr_fc,
                                             out, n, CAPB);
    } else if (ws_size >= cap_needed && deg_ok) {
        int* cnt_sc = (int*)d_ws;
        int* cnt_fc = cnt_sc + n;
        int* csr_sc = cnt_fc + n;
        int* csr_fc = csr_sc + (size_t)n * CAP;

        hipMemsetAsync(cnt_sc, 0, (size_t)2 * n * sizeof(int), stream);

        int eb = 256;
        int eblocks = (E + eb - 1) / eb;
        lp_fill_cap<<<dim3(eblocks, 2), eb, 0, stream>>>(null_mask,
                                                         src_sc, dst_sc, src_fc, dst_fc,
                                                         cnt_sc, cnt_fc, csr_sc, csr_fc, E);
        int nb = 256;
        int nblocks = (int)(((long long)n * 32 + nb - 1) / nb);
        lp_pull_cap<<<nblocks, nb, 0, stream>>>(lbls, null_mask,
                                                cnt_sc, csr_sc, cnt_fc, csr_fc,
                                                out, n, CAP);
    } else {
        float* sums_sc = (float*)d_ws;
        float* sums_fc = sums_sc + (size_t)n * C_CH;
        float* cnt_sc  = sums_fc + (size_t)n * C_CH;
        float* cnt_fc  = cnt_sc + n;
        size_t ws_needed_bytes = ((size_t)n * C_CH * 2 + (size_t)n * 2) * sizeof(float);
        hipMemsetAsync(d_ws, 0, ws_needed_bytes, stream);

        long long threads = (long long)E * 8;
        int block = 256;
        int blocks = (int)((threads + block - 1) / block);
        lp_scatter<<<dim3(blocks, 2), block, 0, stream>>>(lbls, null_mask,
                                                          src_sc, dst_sc, src_fc, dst_fc,
                                                          sums_sc, cnt_sc, sums_fc, cnt_fc, E);
        long long fthreads = (long long)n * 8;
        int fblocks = (int)((fthreads + block - 1) / block);
        lp_finalize<<<fblocks, block, 0, stream>>>(lbls, null_mask,
                                                   sums_sc, cnt_sc, sums_fc, cnt_fc,
                                                   out, n);
    }
}

// Round 23
// 140.463 us; speedup vs baseline: 1.1156x; 1.1152x over previous
//
#include <hip/hip_runtime.h>

#define C_CH 32
#define CAP 128        // capacity-path csr slots per node
#define CAPB 88        // binned-path csr slots per node (Poisson(32), P(>88)~1e-15)
#define BW_LOG 9
#define BW_N (1 << BW_LOG)   // 512 nodes per dst-bucket
#define EPB 8192             // edges per binning workgroup
#define BIN_T 1024           // binning WG size
#define EPT (EPB / BIN_T)    // 8 edges per thread, cached in registers
#define SRC_BITS 17
#define SRC_MASK 0x1FFFF

// =================== binned-CSR path ===================

// Pack null_mask (int32) into a 12.5KB bitmap -> L1-resident for lp_bin's gathers.
__global__ void lp_packmask(const int* __restrict__ mask,
                            unsigned* __restrict__ bits, int n, int nwords)
{
    int i = blockIdx.x * blockDim.x + threadIdx.x;
    int lane = threadIdx.x & 63;
    bool pred = (i < n) && (mask[i] != 0);
    unsigned long long b = __ballot(pred);
    if (lane == 0) {
        int w0 = i >> 5;
        if (w0 < nwords) bits[w0] = (unsigned)b;
        if (w0 + 1 < nwords) bits[w0 + 1] = (unsigned)(b >> 32);
    }
}

// Two-sweep binning; sweep-1 results (keep flag + dst) cached in registers so
// sweep 2 re-reads nothing. Mask lookups hit the L1-resident bitmap.
__global__ void lp_bin(const unsigned* __restrict__ mask_bits,
                       const int* __restrict__ src_sc, const int* __restrict__ dst_sc,
                       const int* __restrict__ src_fc, const int* __restrict__ dst_fc,
                       int* __restrict__ cursors,   // [2*NB]
                       int* __restrict__ bins,      // [2*NB*BCAP]
                       int E, int NB, int BCAP)
{
    const int g = blockIdx.y;
    const int* __restrict__ src = g ? src_fc : src_sc;
    const int* __restrict__ dst = g ? dst_fc : dst_sc;
    extern __shared__ int lds[];        // lhist[NB] | lbase[NB]
    int* lhist = lds;
    int* lbase = lds + NB;
    const int tid = threadIdx.x;
    const long long e0 = (long long)blockIdx.x * EPB;

    for (int b = tid; b < NB; b += BIN_T) lhist[b] = 0;
    __syncthreads();

    unsigned cached[EPT];               // bit31 = keep, low bits = dst
    #pragma unroll
    for (int k = 0; k < EPT; ++k) {
        long long e = e0 + tid + (long long)k * BIN_T;
        unsigned c = 0;
        if (e < E) {
            int d = dst[e];
            if ((mask_bits[d >> 5] >> (d & 31)) & 1u) {
                c = (unsigned)d | 0x80000000u;
                atomicAdd(&lhist[d >> BW_LOG], 1);
            }
        }
        cached[k] = c;
    }
    __syncthreads();
    for (int b = tid; b < NB; b += BIN_T) {
        int k = lhist[b];
        lbase[b] = k ? atomicAdd(&cursors[g * NB + b], k) : 0;
        lhist[b] = 0;
    }
    __syncthreads();
    #pragma unroll
    for (int k = 0; k < EPT; ++k) {
        unsigned c = cached[k];
        if (c & 0x80000000u) {
            int d = (int)(c & 0x7FFFFFFFu);
            int b = d >> BW_LOG;
            long long e = e0 + tid + (long long)k * BIN_T;
            int slot = atomicAdd(&lhist[b], 1);
            long long pos = (long long)lbase[b] + slot;
            if (pos < BCAP) {
                int packed = (src[e] & SRC_MASK) | ((d & (BW_N - 1)) << SRC_BITS);
                bins[(long long)(g * NB + b) * BCAP + pos] = packed;
            }
        }
    }
}

// One WG per (bucket, graph). Per-node ranks via LDS atomics (no global atomics);
// final counts written once with plain contiguous stores.
__global__ void lp_fill_binned(const int* __restrict__ cursors,
                               const int* __restrict__ bins,
                               int* __restrict__ cnt_sc, int* __restrict__ cnt_fc,
                               int* __restrict__ csr_sc, int* __restrict__ csr_fc,
                               int NB, int BCAP, int n)
{
    const int g = blockIdx.y;
    int* __restrict__ cnt = g ? cnt_fc : cnt_sc;
    int* __restrict__ csr = g ? csr_fc : csr_sc;
    const int b = blockIdx.x;
    __shared__ int lcnt[BW_N];
    for (int i = threadIdx.x; i < BW_N; i += blockDim.x) lcnt[i] = 0;
    __syncthreads();

    int m = min(cursors[g * NB + b], BCAP);
    const int* __restrict__ bb = bins + (long long)(g * NB + b) * BCAP;
    for (int i = threadIdx.x; i < m; i += blockDim.x) {
        int p = bb[i];
        int s = p & SRC_MASK;
        int dl = p >> SRC_BITS;                     // node idx within bucket
        int r = atomicAdd(&lcnt[dl], 1);            // LDS atomic
        if (r < CAPB)
            csr[(long long)((b << BW_LOG) + dl) * CAPB + r] = s;
    }
    __syncthreads();
    int base = b << BW_LOG;
    for (int i = threadIdx.x; i < BW_N; i += blockDim.x) {
        int node = base + i;
        if (node < n) cnt[node] = lcnt[i];
    }
}

// f32 -> bf16 (RNE) side table for the gather-heavy pull.
__global__ void lp_tobf16(const float* __restrict__ in,
                          unsigned short* __restrict__ out, int total)
{
    int i = blockIdx.x * blockDim.x + threadIdx.x;
    if (i < total) {
        unsigned u = __float_as_uint(in[i]);
        unsigned r = (u + 0x7FFF + ((u >> 16) & 1)) >> 16;
        out[i] = (unsigned short)r;
    }
}

// 8 lanes per node; each lane owns 4 channels as ushort4 (8B). 64B gather per edge.
// (round-20 proven version: sequential per-graph loops, unconditional 8-load fast path)
__global__ void lp_pull8(const float* __restrict__ lbls,
                         const unsigned short* __restrict__ lb16,
                         const int* __restrict__ null_mask,
                         const int* __restrict__ cnt_sc, const int* __restrict__ csr_sc,
                         const int* __restrict__ cnt_fc, const int* __restrict__ csr_fc,
                         float* __restrict__ out, int n, int cap)
{
    int t = blockIdx.x * blockDim.x + threadIdx.x;
    int node = t >> 3;
    int lane = t & 7;
    if (node >= n) return;

    long long obase = (long long)node * C_CH + lane * 4;
    if (!null_mask[node]) {
        float4 v = *reinterpret_cast<const float4*>(lbls + obase);
        *reinterpret_cast<float4*>(out + obase) = v;
        return;
    }

    float r0 = 0.f, r1 = 0.f, r2 = 0.f, r3 = 0.f;
    #pragma unroll
    for (int g = 0; g < 2; ++g) {
        const int* __restrict__ cnt = g ? cnt_fc : cnt_sc;
        const int* __restrict__ csr = g ? csr_fc : csr_sc;
        int m = min(cnt[node], cap);
        const int* row = csr + (long long)node * cap;
        float a0 = 0.f, a1 = 0.f, a2 = 0.f, a3 = 0.f;
        for (int base = 0; base < m; base += 8) {
            int sidx = (base + lane < m) ? row[base + lane] : 0;
            int lim = min(8, m - base);
            if (lim == 8) {
                #pragma unroll
                for (int k = 0; k < 8; ++k) {
                    int s = __shfl(sidx, k, 8);
                    ushort4 v = *reinterpret_cast<const ushort4*>(
                        lb16 + (long long)s * C_CH + lane * 4);
                    a0 += __uint_as_float((unsigned)v.x << 16);
                    a1 += __uint_as_float((unsigned)v.y << 16);
                    a2 += __uint_as_float((unsigned)v.z << 16);
                    a3 += __uint_as_float((unsigned)v.w << 16);
                }
            } else {
                for (int k = 0; k < lim; ++k) {
                    int s = __shfl(sidx, k, 8);
                    ushort4 v = *reinterpret_cast<const ushort4*>(
                        lb16 + (long long)s * C_CH + lane * 4);
                    a0 += __uint_as_float((unsigned)v.x << 16);
                    a1 += __uint_as_float((unsigned)v.y << 16);
                    a2 += __uint_as_float((unsigned)v.z << 16);
                    a3 += __uint_as_float((unsigned)v.w << 16);
                }
            }
        }
        float inv = 1.0f / fmaxf((float)m, 1.0f);
        r0 += a0 * inv; r1 += a1 * inv; r2 += a2 * inv; r3 += a3 * inv;
    }
    float4 o;
    o.x = r0 * 0.5f; o.y = r1 * 0.5f; o.z = r2 * 0.5f; o.w = r3 * 0.5f;
    *reinterpret_cast<float4*>(out + obase) = o;
}

// =================== capacity-CSR path (fallback #1) ===================

__global__ void lp_fill_cap(const int* __restrict__ null_mask,
                            const int* __restrict__ src_sc, const int* __restrict__ dst_sc,
                            const int* __restrict__ src_fc, const int* __restrict__ dst_fc,
                            int* __restrict__ cnt_sc, int* __restrict__ cnt_fc,
                            int* __restrict__ csr_sc, int* __restrict__ csr_fc, int E)
{
    const int g = blockIdx.y;
    const int* __restrict__ src = g ? src_fc : src_sc;
    const int* __restrict__ dst = g ? dst_fc : dst_sc;
    int* __restrict__ cnt = g ? cnt_fc : cnt_sc;
    int* __restrict__ csr = g ? csr_fc : csr_sc;
    int e = blockIdx.x * blockDim.x + threadIdx.x;
    if (e >= E) return;
    int d = dst[e];
    if (!null_mask[d]) return;
    int r = atomicAdd(&cnt[d], 1);
    if (r < CAP) csr[(long long)d * CAP + r] = src[e];
}

__global__ void lp_pull_cap(const float* __restrict__ lbls,
                            const int* __restrict__ null_mask,
                            const int* __restrict__ cnt_sc, const int* __restrict__ csr_sc,
                            const int* __restrict__ cnt_fc, const int* __restrict__ csr_fc,
                            float* __restrict__ out, int n, int cap)
{
    int node = (blockIdx.x * blockDim.x + threadIdx.x) >> 5;
    int lane = threadIdx.x & 31;
    if (node >= n) return;
    long long obase = (long long)node * C_CH + lane;
    if (!null_mask[node]) {
        out[obase] = lbls[obase];
        return;
    }
    float means[2];
    #pragma unroll
    for (int g = 0; g < 2; ++g) {
        const int* __restrict__ cnt = g ? cnt_fc : cnt_sc;
        const int* __restrict__ csr = g ? csr_fc : csr_sc;
        int m = min(cnt[node], cap);
        const int* row = csr + (long long)node * cap;
        float acc = 0.0f;
        for (int base = 0; base < m; base += 32) {
            int sidx = (base + lane < m) ? row[base + lane] : 0;
            int lim = min(32, m - base);
            if (lim == 32) {
                #pragma unroll
                for (int k = 0; k < 32; ++k) {
                    int s = __shfl(sidx, k, 32);
                    acc += lbls[(long long)s * C_CH + lane];
                }
            } else {
                for (int k = 0; k < lim; ++k) {
                    int s = __shfl(sidx, k, 32);
                    acc += lbls[(long long)s * C_CH + lane];
                }
            }
        }
        means[g] = acc / fmaxf((float)m, 1.0f);
    }
    out[obase] = 0.5f * (means[0] + means[1]);
}

// =================== push-atomic path (fallback #2) ===================

__global__ void lp_scatter(const float* __restrict__ lbls,
                           const int* __restrict__ null_mask,
                           const int* __restrict__ src_sc, const int* __restrict__ dst_sc,
                           const int* __restrict__ src_fc, const int* __restrict__ dst_fc,
                           float* __restrict__ sums_sc, float* __restrict__ cnt_sc,
                           float* __restrict__ sums_fc, float* __restrict__ cnt_fc,
                           int E)
{
    const int g = blockIdx.y;
    const int* __restrict__ src = g ? src_fc : src_sc;
    const int* __restrict__ dst = g ? dst_fc : dst_sc;
    float* __restrict__ sums = g ? sums_fc : sums_sc;
    float* __restrict__ cnt  = g ? cnt_fc  : cnt_sc;
    long long tid = (long long)blockIdx.x * blockDim.x + threadIdx.x;
    long long e = tid >> 3;
    int sub = (int)(tid & 7);
    if (e >= E) return;
    int d = dst[e];
    if (!null_mask[d]) return;
    int s = src[e];
    const float4 v = *reinterpret_cast<const float4*>(lbls + (long long)s * C_CH + sub * 4);
    float* base = sums + (long long)d * C_CH + sub * 4;
    atomicAdd(base + 0, v.x);
    atomicAdd(base + 1, v.y);
    atomicAdd(base + 2, v.z);
    atomicAdd(base + 3, v.w);
    if (sub == 0) atomicAdd(cnt + d, 1.0f);
}

__global__ void lp_finalize(const float* __restrict__ lbls,
                            const int* __restrict__ null_mask,
                            const float* __restrict__ sums_sc, const float* __restrict__ cnt_sc,
                            const float* __restrict__ sums_fc, const float* __restrict__ cnt_fc,
                            float* __restrict__ out, int n)
{
    long long tid = (long long)blockIdx.x * blockDim.x + threadIdx.x;
    long long node = tid >> 3;
    int sub = (int)(tid & 7);
    if (node >= n) return;
    long long off = node * C_CH + sub * 4;
    float4 o;
    if (null_mask[node]) {
        float inv1 = 1.0f / fmaxf(cnt_sc[node], 1.0f);
        float inv2 = 1.0f / fmaxf(cnt_fc[node], 1.0f);
        float4 s1 = *reinterpret_cast<const float4*>(sums_sc + off);
        float4 s2 = *reinterpret_cast<const float4*>(sums_fc + off);
        o.x = (s1.x * inv1 + s2.x * inv2) * 0.5f;
        o.y = (s1.y * inv1 + s2.y * inv2) * 0.5f;
        o.z = (s1.z * inv1 + s2.z * inv2) * 0.5f;
        o.w = (s1.w * inv1 + s2.w * inv2) * 0.5f;
    } else {
        o = *reinterpret_cast<const float4*>(lbls + off);
    }
    *reinterpret_cast<float4*>(out + off) = o;
}

// =================== launch ===================

extern "C" void kernel_launch(void* const* d_in, const int* in_sizes, int n_in,
                              void* d_out, int out_size, void* d_ws, size_t ws_size,
                              hipStream_t stream) {
    const float* lbls    = (const float*)d_in[0];
    const int* null_mask = (const int*)d_in[1];   // jax bool -> int32 on the wire
    const int* src_sc    = (const int*)d_in[2];
    const int* dst_sc    = (const int*)d_in[3];
    const int* src_fc    = (const int*)d_in[4];
    const int* dst_fc    = (const int*)d_in[5];
    float* out           = (float*)d_out;

    const int n = in_sizes[1];      // 100000 nodes
    const int E = in_sizes[2];      // 3.2M edges per graph

    // ---- binned path sizing
    const int NB = (n + BW_N - 1) >> BW_LOG;
    const int BCAP = (int)((long long)E * BW_N / n) + 2048;
    const int NWORDS = (n + 31) / 32;
    size_t binned_needed = ((size_t)2 * n + (size_t)2 * NB
                            + (size_t)2 * NB * BCAP + (size_t)2 * n * CAPB) * sizeof(int)
                           + (size_t)n * C_CH * sizeof(unsigned short)
                           + (size_t)NWORDS * sizeof(unsigned);
    size_t lds_bytes = (size_t)2 * NB * sizeof(int);
    bool bin_ok = (n <= (1 << SRC_BITS)) && (lds_bytes <= 60 * 1024) && NB <= 65535;

    size_t cap_needed = ((size_t)2 * n + (size_t)2 * n * CAP) * sizeof(int);
    bool deg_ok = ((long long)E / n) * 3 + 32 <= CAP;

    if (ws_size >= binned_needed && bin_ok) {
        int* cnt_sc  = (int*)d_ws;
        int* cnt_fc  = cnt_sc + n;
        int* cursors = cnt_fc + n;
        int* bins    = cursors + (size_t)2 * NB;
        int* csr_sc  = bins + (size_t)2 * NB * BCAP;
        int* csr_fc  = csr_sc + (size_t)n * CAPB;
        unsigned short* lb16 = (unsigned short*)(csr_fc + (size_t)n * CAPB);
        unsigned* mask_bits = (unsigned*)(lb16 + (size_t)n * C_CH);

        // only cursors need zeroing (fill writes every cnt slot)
        hipMemsetAsync(cursors, 0, (size_t)2 * NB * sizeof(int), stream);

        int total16 = n * C_CH;
        lp_tobf16<<<(total16 + 255) / 256, 256, 0, stream>>>(lbls, lb16, total16);
        lp_packmask<<<(n + 255) / 256, 256, 0, stream>>>(null_mask, mask_bits, n, NWORDS);

        int nwg_bin = (E + EPB - 1) / EPB;
        lp_bin<<<dim3(nwg_bin, 2), BIN_T, (int)lds_bytes, stream>>>(
            mask_bits, src_sc, dst_sc, src_fc, dst_fc, cursors, bins, E, NB, BCAP);
        lp_fill_binned<<<dim3(NB, 2), 256, 0, stream>>>(
            cursors, bins, cnt_sc, cnt_fc, csr_sc, csr_fc, NB, BCAP, n);

        int nb = 256;
        int nblocks = (int)(((long long)n * 8 + nb - 1) / nb);
        lp_pull8<<<nblocks, nb, 0, stream>>>(lbls, lb16, null_mask,
                                             cnt_sc, csr_sc, cnt_fc, csr_fc,
                                             out, n, CAPB);
    } else if (ws_size >= cap_needed && deg_ok) {
        int* cnt_sc = (int*)d_ws;
        int* cnt_fc = cnt_sc + n;
        int* csr_sc = cnt_fc + n;
        int* csr_fc = csr_sc + (size_t)n * CAP;

        hipMemsetAsync(cnt_sc, 0, (size_t)2 * n * sizeof(int), stream);

        int eb = 256;
        int eblocks = (E + eb - 1) / eb;
        lp_fill_cap<<<dim3(eblocks, 2), eb, 0, stream>>>(null_mask,
                                                         src_sc, dst_sc, src_fc, dst_fc,
                                                         cnt_sc, cnt_fc, csr_sc, csr_fc, E);
        int nb = 256;
        int nblocks = (int)(((long long)n * 32 + nb - 1) / nb);
        lp_pull_cap<<<nblocks, nb, 0, stream>>>(lbls, null_mask,
                                                cnt_sc, csr_sc, cnt_fc, csr_fc,
                                                out, n, CAP);
    } else {
        float* sums_sc = (float*)d_ws;
        float* sums_fc = sums_sc + (size_t)n * C_CH;
        float* cnt_sc  = sums_fc + (size_t)n * C_CH;
        float* cnt_fc  = cnt_sc + n;
        size_t ws_needed_bytes = ((size_t)n * C_CH * 2 + (size_t)n * 2) * sizeof(float);
        hipMemsetAsync(d_ws, 0, ws_needed_bytes, stream);

        long long threads = (long long)E * 8;
        int block = 256;
        int blocks = (int)((threads + block - 1) / block);
        lp_scatter<<<dim3(blocks, 2), block, 0, stream>>>(lbls, null_mask,
                                                          src_sc, dst_sc, src_fc, dst_fc,
                                                          sums_sc, cnt_sc, sums_fc, cnt_fc, E);
        long long fthreads = (long long)n * 8;
        int fblocks = (int)((fthreads + block - 1) / block);
        lp_finalize<<<fblocks, block, 0, stream>>>(lbls, null_mask,
                                                   sums_sc, cnt_sc, sums_fc, cnt_fc,
                                                   out, n);
    }
}